// Round 9
// baseline (167.557 us; speedup 1.0000x reference)
//
#include <hip/hip_runtime.h>
#include <hip/hip_bf16.h>

// B=4, H=W=56, C=256, 7x7 windows of 8x8, 8 heads x 32, top-4.
// Inputs fp32; d_out fp32. Intermediates bf16; MFMA bf16 w/ fp32 accum.
// 4-launch pipeline: prep -> [qkv_gemm | winproj+route] -> attn(+lepe) -> proj
#define NPIX 12544   // B*56*56

typedef short bf16x8 __attribute__((ext_vector_type(8)));
typedef float f32x4  __attribute__((ext_vector_type(4)));

__device__ __forceinline__ float bf2f(unsigned short u) {
    unsigned int x = ((unsigned int)u) << 16;
    float f; __builtin_memcpy(&f, &x, sizeof(f)); return f;
}
__device__ __forceinline__ unsigned short f2bf(float f) {
    __hip_bfloat16 h = __float2bfloat16(f);
    unsigned short u; __builtin_memcpy(&u, &h, 2); return u;
}
// async global->LDS DMA, 16B per lane; LDS dest is wave-uniform base + lane*16
__device__ __forceinline__ void load_lds16(const unsigned short* g, unsigned short* l) {
    __builtin_amdgcn_global_load_lds(
        (const __attribute__((address_space(1))) unsigned int*)g,
        (__attribute__((address_space(3))) unsigned int*)l,
        16, 0, 0);
}

// ---------------------------------------------------------------------------
// K0: fused prep.
//   blocks 0..391   : x -> bf16 + per-window mean (2 blocks/window, 128 ch each)
//   blocks 392..439 : Wqkv^T tiles (64x64 LDS transpose)
//   blocks 440..455 : Wo^T tiles
// ---------------------------------------------------------------------------
__global__ __launch_bounds__(256) void k_prep(
    const float* __restrict__ X, unsigned short* __restrict__ Xb,
    float* __restrict__ xmean,
    const float* __restrict__ Wqkv, const float* __restrict__ Wo,
    unsigned short* __restrict__ Wtq, unsigned short* __restrict__ Wto)
{
    __shared__ __align__(16) unsigned char sm[64 * 65 * 4];   // 16.6 KB union
    const int t = threadIdx.x;
    const int blk = blockIdx.x;
    if (blk < 392) {
        float* part = (float*)sm;                 // [8 ps][32 cg][4]
        const int w = blk >> 1, hc = blk & 1;
        const int b = w / 49, p = w % 49;
        const int wi = p / 7, wj = p % 7;
        const int ch0 = hc * 128;
        const int ps = t >> 5, cg = t & 31;
        float4 s = {0.f, 0.f, 0.f, 0.f};
        #pragma unroll
        for (int i = 0; i < 8; i++) {
            int pp = ps * 8 + i;
            int y = wi * 8 + (pp >> 3), x = wj * 8 + (pp & 7);
            int idx = (((b * 56) + y) * 56 + x) * 256 + ch0 + cg * 4;
            float4 v = *reinterpret_cast<const float4*>(X + idx);
            s.x += v.x; s.y += v.y; s.z += v.z; s.w += v.w;
            ushort4 o = { f2bf(v.x), f2bf(v.y), f2bf(v.z), f2bf(v.w) };
            *reinterpret_cast<ushort4*>(Xb + idx) = o;
        }
        *reinterpret_cast<float4*>(part + t * 4) = *reinterpret_cast<float4*>(&s);
        __syncthreads();
        if (t < 32) {
            float4 m = {0.f, 0.f, 0.f, 0.f};
            #pragma unroll
            for (int ps2 = 0; ps2 < 8; ps2++) {
                float4 v = *reinterpret_cast<float4*>(part + (ps2 * 32 + t) * 4);
                m.x += v.x; m.y += v.y; m.z += v.z; m.w += v.w;
            }
            m.x *= (1.f / 64.f); m.y *= (1.f / 64.f);
            m.z *= (1.f / 64.f); m.w *= (1.f / 64.f);
            *reinterpret_cast<float4*>(xmean + w * 256 + ch0 + t * 4) = m;
        }
    } else {
        float* tile = (float*)sm;                 // [64][65]
        int tb = blk - 392;
        const float* Wsrc; unsigned short* Wdst; int N, kt, nt;
        if (tb < 48) { Wsrc = Wqkv; Wdst = Wtq; N = 768; kt = tb / 12; nt = tb % 12; }
        else { tb -= 48; Wsrc = Wo; Wdst = Wto; N = 256; kt = tb / 4; nt = tb % 4; }
        const int k0 = kt * 64, n0 = nt * 64;
        const int r0 = t >> 6, c = t & 63;
        #pragma unroll
        for (int i = 0; i < 16; i++) {
            int r = i * 4 + r0;
            tile[r * 65 + c] = Wsrc[(size_t)(k0 + r) * N + n0 + c];
        }
        __syncthreads();
        #pragma unroll
        for (int i = 0; i < 16; i++) {
            int n = i * 4 + r0;
            Wdst[(size_t)(n0 + n) * 256 + k0 + c] = f2bf(tile[c * 65 + n]);
        }
    }
}

// ---------------------------------------------------------------------------
// K1: merged launch — qkv GEMM (blocks 0..587) | winproj+route (blocks 588..783)
//   Route math: logit[p][q] ∝ qwin[p] · (xmean[q] @ Wk).
//   qwin[p] = xmean[p]@Wq + bq (fp32 exact);  u = Wk^T · qwin[p];
//   lg[q] = xmean[q]·u.  (scale and q-independent bias terms dropped:
//   they don't change top-k ordering.)
// ---------------------------------------------------------------------------
__global__ __launch_bounds__(256) void k_main1(
    const unsigned short* __restrict__ A,   // xb [12544][256]
    const unsigned short* __restrict__ Bt,  // Wtq [768][256]
    const float* __restrict__ bias,         // bqkv [768]
    unsigned short* __restrict__ O,         // qkv bf16
    const float* __restrict__ xmean,        // [196][256]
    const float* __restrict__ Wqkv,         // fp32 [256][768]
    int* __restrict__ ridx)
{
    __shared__ __align__(16) unsigned char sm1[16384];
    const int t = threadIdx.x;
    const int blk = blockIdx.x;
    if (blk < 588) {
        unsigned short* As = (unsigned short*)sm1;          // [128*32]
        unsigned short* Bs = (unsigned short*)(sm1 + 8192); // [128*32]
        const int m0 = (blk % 98) * 128, n0 = (blk / 98) * 128;
        const int wave = t >> 6, lane = t & 63, quad = lane >> 4, lo = lane & 15;
        const int wm = wave & 1, wn = wave >> 1;
        const int sr = wave * 16 + (lane >> 2);
        const int sc = lane & 3;
        f32x4 acc[4][4];
        #pragma unroll
        for (int i = 0; i < 4; i++)
            #pragma unroll
            for (int j = 0; j < 4; j++) acc[i][j] = (f32x4){0.f, 0.f, 0.f, 0.f};

        for (int kt = 0; kt < 256; kt += 32) {
            __syncthreads();
            #pragma unroll
            for (int j = 0; j < 2; j++) {
                int row = j * 64 + sr;
                int e = sc ^ ((row >> 1) & 3);
                load_lds16(A  + (size_t)(m0 + row) * 256 + kt + e * 8, &As[row * 32 + sc * 8]);
                load_lds16(Bt + (size_t)(n0 + row) * 256 + kt + e * 8, &Bs[row * 32 + sc * 8]);
            }
            __syncthreads();
            bf16x8 af[4], bfr[4];
            #pragma unroll
            for (int mt = 0; mt < 4; mt++) {
                int row = wm * 64 + mt * 16 + lo;
                int c = quad ^ ((row >> 1) & 3);
                af[mt] = *reinterpret_cast<const bf16x8*>(&As[row * 32 + c * 8]);
            }
            #pragma unroll
            for (int nt = 0; nt < 4; nt++) {
                int col = wn * 64 + nt * 16 + lo;
                int c = quad ^ ((col >> 1) & 3);
                bfr[nt] = *reinterpret_cast<const bf16x8*>(&Bs[col * 32 + c * 8]);
            }
            #pragma unroll
            for (int mt = 0; mt < 4; mt++)
                #pragma unroll
                for (int nt = 0; nt < 4; nt++)
                    acc[mt][nt] = __builtin_amdgcn_mfma_f32_16x16x32_bf16(
                        af[mt], bfr[nt], acc[mt][nt], 0, 0, 0);
        }
        float bv[4];
        #pragma unroll
        for (int nt = 0; nt < 4; nt++) bv[nt] = bias[n0 + wn * 64 + nt * 16 + lo];
        #pragma unroll
        for (int mt = 0; mt < 4; mt++)
            #pragma unroll
            for (int nt = 0; nt < 4; nt++) {
                int n = n0 + wn * 64 + nt * 16 + lo;
                #pragma unroll
                for (int r = 0; r < 4; r++) {
                    int m = m0 + wm * 64 + mt * 16 + quad * 4 + r;
                    O[m * 768 + n] = f2bf(acc[mt][nt][r] + bv[nt]);
                }
            }
    } else {
        float* xq   = (float*)sm1;                 // [256]
        float* qs   = (float*)(sm1 + 1024);        // [256]
        float* us   = (float*)(sm1 + 2048);        // [256]
        float* part = (float*)(sm1 + 3072);        // [49][4]
        float* lg   = (float*)(sm1 + 3072 + 784);  // [49]
        const int u = blk - 588;                   // 0..195 = b*49 + p
        const int b = u / 49;
        xq[t] = xmean[(size_t)u * 256 + t];
        __syncthreads();
        {   // qwin[p][t] (fp32 exact, includes q-bias)
            float a = 0.f;
            for (int k = 0; k < 256; k++) a += xq[k] * Wqkv[k * 768 + t];
            qs[t] = a + bias[t];
        }
        __syncthreads();
        {   // u[t] = sum_c qs[c] * Wk[t][c]
            const float* wr = Wqkv + (size_t)t * 768 + 256;
            float a = 0.f;
            for (int c = 0; c < 256; c += 4) {
                float4 w = *reinterpret_cast<const float4*>(wr + c);
                a += qs[c] * w.x + qs[c + 1] * w.y + qs[c + 2] * w.z + qs[c + 3] * w.w;
            }
            us[t] = a;
        }
        __syncthreads();
        if (t < 196) {   // lg[d] = xmean[b,d] · u  (4 partial lanes per d)
            int d = t >> 2, pr = t & 3;
            const float* xm = xmean + (size_t)(b * 49 + d) * 256 + pr * 64;
            float a = 0.f;
            for (int k = 0; k < 64; k++) a += xm[k] * us[pr * 64 + k];
            part[d * 4 + pr] = a;
        }
        __syncthreads();
        if (t < 49) lg[t] = part[t * 4] + part[t * 4 + 1] + part[t * 4 + 2] + part[t * 4 + 3];
        __syncthreads();
        if (t == 0) {
            unsigned long long used = 0ull;
            for (int sel = 0; sel < 4; sel++) {
                float best = -1e30f; int bi = 0;
                for (int qq = 0; qq < 49; qq++)
                    if (!((used >> qq) & 1ull) && lg[qq] > best) { best = lg[qq]; bi = qq; }
                used |= (1ull << bi);
                ridx[u * 4 + sel] = bi;
            }
        }
    }
}

// ---------------------------------------------------------------------------
// K6: MFMA gathered window attention + fused depthwise-5x5 LEPE -> Osum
// ---------------------------------------------------------------------------
__global__ __launch_bounds__(256) void k_attn(
    const unsigned short* __restrict__ QKV,
    const int* __restrict__ ridx,
    const float* __restrict__ lw, const float* __restrict__ lb,
    unsigned short* __restrict__ Osum)
{
    __shared__ __align__(16) unsigned char smem[50688];
    unsigned short* Vt = (unsigned short*)smem;                  // [32][264]
    unsigned short* Qs = (unsigned short*)(smem + 16896);        // [64][40]
    unsigned short* Ks = (unsigned short*)(smem + 22016);        // [256][40]
    unsigned short* Ps = (unsigned short*)(smem + 16896);        // 4 x [16][264]

    const int p = blockIdx.x, head = blockIdx.y, b = blockIdx.z;
    const int t = threadIdx.x;
    const int wi = p / 7, wj = p % 7;
    const int wave = t >> 6, lane = t & 63, quad = lane >> 4, lo = lane & 15;
    const int pix4 = t >> 2, c4 = t & 3;

    {
        int y = wi * 8 + (pix4 >> 3), x = wj * 8 + (pix4 & 7);
        const unsigned short* qp = QKV + (((b * 56) + y) * 56 + x) * 768 + head * 32 + c4 * 8;
        bf16x8 v = *reinterpret_cast<const bf16x8*>(qp);
        int sw = c4 ^ ((pix4 >> 3) & 3);
        *reinterpret_cast<bf16x8*>(&Qs[pix4 * 40 + sw * 8]) = v;
    }
    #pragma unroll
    for (int pass = 0; pass < 4; pass++) {
        int sel = ridx[(b * 49 + p) * 4 + pass];
        int si = sel / 7, sj = sel % 7;
        int y = si * 8 + (pix4 >> 3), x = sj * 8 + (pix4 & 7);
        const unsigned short* base = QKV + (((b * 56) + y) * 56 + x) * 768 + 256 + head * 32;
        bf16x8 kv = *reinterpret_cast<const bf16x8*>(base + c4 * 8);
        bf16x8 vv = *reinterpret_cast<const bf16x8*>(base + 256 + c4 * 8);
        int krow = pass * 64 + pix4;
        int sw = c4 ^ ((krow >> 3) & 3);
        *reinterpret_cast<bf16x8*>(&Ks[krow * 40 + sw * 8]) = kv;
        #pragma unroll
        for (int j = 0; j < 8; j++)
            Vt[(c4 * 8 + j) * 264 + krow] = (unsigned short)vv[j];
    }
    __syncthreads();

    f32x4 sc[16];
    {
        int row = wave * 16 + lo;
        bf16x8 af = *reinterpret_cast<const bf16x8*>(
            &Qs[row * 40 + ((quad ^ ((row >> 3) & 3)) * 8)]);
        f32x4 z = (f32x4){0.f, 0.f, 0.f, 0.f};
        #pragma unroll
        for (int nt = 0; nt < 16; nt++) {
            int key = nt * 16 + lo;
            bf16x8 bfr = *reinterpret_cast<const bf16x8*>(
                &Ks[key * 40 + ((quad ^ ((key >> 3) & 3)) * 8)]);
            sc[nt] = __builtin_amdgcn_mfma_f32_16x16x32_bf16(af, bfr, z, 0, 0, 0);
        }
    }
    float M[4] = {-1e30f, -1e30f, -1e30f, -1e30f};
    #pragma unroll
    for (int nt = 0; nt < 16; nt++)
        #pragma unroll
        for (int r = 0; r < 4; r++) M[r] = fmaxf(M[r], sc[nt][r] * 0.0625f);
    #pragma unroll
    for (int d = 1; d < 16; d <<= 1)
        #pragma unroll
        for (int r = 0; r < 4; r++) M[r] = fmaxf(M[r], __shfl_xor(M[r], d));
    float l[4] = {0.f, 0.f, 0.f, 0.f};
    #pragma unroll
    for (int nt = 0; nt < 16; nt++)
        #pragma unroll
        for (int r = 0; r < 4; r++) {
            float e = __expf(sc[nt][r] * 0.0625f - M[r]);
            sc[nt][r] = e;
            l[r] += e;
        }
    #pragma unroll
    for (int d = 1; d < 16; d <<= 1)
        #pragma unroll
        for (int r = 0; r < 4; r++) l[r] += __shfl_xor(l[r], d);

    __syncthreads();   // all waves done reading Qs/Ks -> Ps may overwrite

    unsigned short* myPs = Ps + wave * 16 * 264;
    #pragma unroll
    for (int nt = 0; nt < 16; nt++)
        #pragma unroll
        for (int r = 0; r < 4; r++)
            myPs[(quad * 4 + r) * 264 + nt * 16 + lo] = f2bf(sc[nt][r]);
    // (no barrier: PV reads only this wave's own Ps tile)

    f32x4 o0 = (f32x4){0.f, 0.f, 0.f, 0.f}, o1 = o0;
    #pragma unroll
    for (int kt = 0; kt < 8; kt++) {
        bf16x8 pa = *reinterpret_cast<const bf16x8*>(
            &myPs[lo * 264 + kt * 32 + quad * 8]);
        bf16x8 vb0 = *reinterpret_cast<const bf16x8*>(
            &Vt[lo * 264 + kt * 32 + quad * 8]);
        bf16x8 vb1 = *reinterpret_cast<const bf16x8*>(
            &Vt[(16 + lo) * 264 + kt * 32 + quad * 8]);
        o0 = __builtin_amdgcn_mfma_f32_16x16x32_bf16(pa, vb0, o0, 0, 0, 0);
        o1 = __builtin_amdgcn_mfma_f32_16x16x32_bf16(pa, vb1, o1, 0, 0, 0);
    }

    // ---- fused LEPE: 12x12 V-halo + bf16 weights into dead LDS regions ----
    __syncthreads();   // everyone done reading Vt / Ps
    unsigned short* Vimg = (unsigned short*)smem;            // [144][40]
    unsigned short* lwsb = (unsigned short*)(smem + 16896);  // [25][32]
    unsigned short* lepb = (unsigned short*)(smem + 18496);  // [64][40]
    if (t < 200) {
        int tap = t >> 3, c = (t & 7) * 4;
        float4 w = *reinterpret_cast<const float4*>(lw + tap * 256 + head * 32 + c);
        unsigned short* dst = &lwsb[tap * 32 + c];
        dst[0] = f2bf(w.x); dst[1] = f2bf(w.y); dst[2] = f2bf(w.z); dst[3] = f2bf(w.w);
    }
    {
        const int y0 = wi * 8 - 2, x0 = wj * 8 - 2;
        #pragma unroll
        for (int i = 0; i < 3; i++) {
            int idx = i * 256 + t;
            if (idx < 576) {
                int pp = idx >> 2, cc = idx & 3;
                int py = y0 + pp / 12, px = x0 + pp % 12;
                bf16x8 v = (bf16x8){0, 0, 0, 0, 0, 0, 0, 0};
                if (py >= 0 && py < 56 && px >= 0 && px < 56)
                    v = *reinterpret_cast<const bf16x8*>(
                        QKV + (((b * 56) + py) * 56 + px) * 768 + 512 + head * 32 + cc * 8);
                *reinterpret_cast<bf16x8*>(&Vimg[pp * 40 + cc * 8]) = v;
            }
        }
    }
    __syncthreads();
    {   // depthwise 5x5 for own 64 pixels, 8 ch per thread
        const int qpix = t >> 2, cc = t & 3;
        const int qy = qpix >> 3, qx = qpix & 7;
        float accl[8];
        float4 b0 = *reinterpret_cast<const float4*>(lb + head * 32 + cc * 8);
        float4 b1 = *reinterpret_cast<const float4*>(lb + head * 32 + cc * 8 + 4);
        accl[0] = b0.x; accl[1] = b0.y; accl[2] = b0.z; accl[3] = b0.w;
        accl[4] = b1.x; accl[5] = b1.y; accl[6] = b1.z; accl[7] = b1.w;
        #pragma unroll
        for (int ky = 0; ky < 5; ky++)
            #pragma unroll
            for (int kx = 0; kx < 5; kx++) {
                int pp = (qy + ky) * 12 + (qx + kx);
                bf16x8 v = *reinterpret_cast<const bf16x8*>(&Vimg[pp * 40 + cc * 8]);
                bf16x8 w = *reinterpret_cast<const bf16x8*>(&lwsb[(ky * 5 + kx) * 32 + cc * 8]);
                #pragma unroll
                for (int j = 0; j < 8; j++)
                    accl[j] += bf2f((unsigned short)v[j]) * bf2f((unsigned short)w[j]);
            }
        bf16x8 o;
        #pragma unroll
        for (int j = 0; j < 8; j++) o[j] = (short)f2bf(accl[j]);
        *reinterpret_cast<bf16x8*>(&lepb[qpix * 40 + cc * 8]) = o;
    }
    __syncthreads();

    #pragma unroll
    for (int r = 0; r < 4; r++) {
        int q = wave * 16 + quad * 4 + r;
        int y = wi * 8 + (q >> 3), x = wj * 8 + (q & 7);
        unsigned short* op = Osum + (size_t)(((b * 56) + y) * 56 + x) * 256 + head * 32;
        float inv = 1.0f / l[r];
        float le0 = bf2f(lepb[q * 40 + lo]);
        float le1 = bf2f(lepb[q * 40 + 16 + lo]);
        op[lo]      = f2bf(o0[r] * inv + le0);
        op[16 + lo] = f2bf(o1[r] * inv + le1);
    }
}

// ---------------------------------------------------------------------------
// K7: out proj (MFMA): Osum[12544,256] @ Wo[256,256] + bo -> fp32 out
// ---------------------------------------------------------------------------
__global__ __launch_bounds__(256) void k_proj(
    const unsigned short* __restrict__ A,
    const unsigned short* __restrict__ Bt,   // Wto [256][256]
    const float* __restrict__ bias,
    float* __restrict__ O)
{
    __shared__ unsigned short As[128 * 32];
    __shared__ unsigned short Bs[64 * 32];
    const int t = threadIdx.x;
    const int m0 = blockIdx.x * 128, n0 = blockIdx.y * 64;
    const int wave = t >> 6, lane = t & 63, quad = lane >> 4, lo = lane & 15;
    const int sr = wave * 16 + (lane >> 2);
    const int sc = lane & 3;
    f32x4 acc[2][4];
    #pragma unroll
    for (int i = 0; i < 2; i++)
        #pragma unroll
        for (int j = 0; j < 4; j++) acc[i][j] = (f32x4){0.f, 0.f, 0.f, 0.f};

    for (int kt = 0; kt < 256; kt += 32) {
        __syncthreads();
        #pragma unroll
        for (int j = 0; j < 2; j++) {
            int row = j * 64 + sr;
            int e = sc ^ ((row >> 1) & 3);
            load_lds16(A + (size_t)(m0 + row) * 256 + kt + e * 8, &As[row * 32 + sc * 8]);
        }
        {
            int e = sc ^ ((sr >> 1) & 3);
            load_lds16(Bt + (size_t)(n0 + sr) * 256 + kt + e * 8, &Bs[sr * 32 + sc * 8]);
        }
        __syncthreads();
        bf16x8 af[2], bfr[4];
        #pragma unroll
        for (int mt = 0; mt < 2; mt++) {
            int row = wave * 32 + mt * 16 + lo;
            int c = quad ^ ((row >> 1) & 3);
            af[mt] = *reinterpret_cast<const bf16x8*>(&As[row * 32 + c * 8]);
        }
        #pragma unroll
        for (int nt = 0; nt < 4; nt++) {
            int col = nt * 16 + lo;
            int c = quad ^ ((col >> 1) & 3);
            bfr[nt] = *reinterpret_cast<const bf16x8*>(&Bs[col * 32 + c * 8]);
        }
        #pragma unroll
        for (int mt = 0; mt < 2; mt++)
            #pragma unroll
            for (int nt = 0; nt < 4; nt++)
                acc[mt][nt] = __builtin_amdgcn_mfma_f32_16x16x32_bf16(
                    af[mt], bfr[nt], acc[mt][nt], 0, 0, 0);
    }
    float bv[4];
    #pragma unroll
    for (int nt = 0; nt < 4; nt++) bv[nt] = bias[n0 + nt * 16 + lo];
    #pragma unroll
    for (int mt = 0; mt < 2; mt++)
        #pragma unroll
        for (int nt = 0; nt < 4; nt++) {
            int n = n0 + nt * 16 + lo;
            #pragma unroll
            for (int r = 0; r < 4; r++) {
                int m = m0 + wave * 32 + mt * 16 + quad * 4 + r;
                O[m * 256 + n] = acc[mt][nt][r] + bv[nt];
            }
        }
}

// ---------------------------------------------------------------------------
extern "C" void kernel_launch(void* const* d_in, const int* in_sizes, int n_in,
                              void* d_out, int out_size, void* d_ws, size_t ws_size,
                              hipStream_t stream)
{
    const float* x    = (const float*)d_in[0];
    const float* Wqkv = (const float*)d_in[1];
    const float* bqkv = (const float*)d_in[2];
    const float* Wo   = (const float*)d_in[3];
    const float* bo   = (const float*)d_in[4];
    const float* lw   = (const float*)d_in[5];
    const float* lb   = (const float*)d_in[6];
    float* out = (float*)d_out;

    char* ws = (char*)d_ws;
    size_t off = 0;
    unsigned short* qkv   = (unsigned short*)(ws + off); off += (size_t)NPIX * 768 * 2;
    unsigned short* xb    = (unsigned short*)(ws + off); off += (size_t)NPIX * 256 * 2;
    unsigned short* Wtq   = (unsigned short*)(ws + off); off += 768 * 256 * 2;
    unsigned short* Wto   = (unsigned short*)(ws + off); off += 256 * 256 * 2;
    unsigned short* Osum  = (unsigned short*)(ws + off); off += (size_t)NPIX * 256 * 2;
    float* xmean = (float*)(ws + off); off += 196 * 256 * 4;
    int*   ridx  = (int*)(ws + off);   off += 196 * 4 * 4;

    k_prep <<<dim3(456),      256, 0, stream>>>(x, xb, xmean, Wqkv, Wo, Wtq, Wto);
    k_main1<<<dim3(784),      256, 0, stream>>>(xb, Wtq, bqkv, qkv, xmean, Wqkv, ridx);
    k_attn <<<dim3(49, 8, 4), 256, 0, stream>>>(qkv, ridx, lw, lb, Osum);
    k_proj <<<dim3(98, 4),    256, 0, stream>>>(Osum, Wto, bo, out);
}

// Round 10
// 160.445 us; speedup vs baseline: 1.0443x; 1.0443x over previous
//
#include <hip/hip_runtime.h>
#include <hip/hip_bf16.h>

// B=4, H=W=56, C=256, 7x7 windows of 8x8, 8 heads x 32, top-4.
// Inputs fp32; d_out fp32. Intermediates bf16; MFMA bf16 w/ fp32 accum.
// 4-launch pipeline: prep -> [qkv_gemm | winproj+route] -> attn(+lepe) -> proj
#define NPIX 12544   // B*56*56

typedef short bf16x8 __attribute__((ext_vector_type(8)));
typedef float f32x4  __attribute__((ext_vector_type(4)));

__device__ __forceinline__ float bf2f(unsigned short u) {
    unsigned int x = ((unsigned int)u) << 16;
    float f; __builtin_memcpy(&f, &x, sizeof(f)); return f;
}
__device__ __forceinline__ unsigned short f2bf(float f) {
    __hip_bfloat16 h = __float2bfloat16(f);
    unsigned short u; __builtin_memcpy(&u, &h, 2); return u;
}
// async global->LDS DMA, 16B per lane; LDS dest is wave-uniform base + lane*16
__device__ __forceinline__ void load_lds16(const unsigned short* g, unsigned short* l) {
    __builtin_amdgcn_global_load_lds(
        (const __attribute__((address_space(1))) unsigned int*)g,
        (__attribute__((address_space(3))) unsigned int*)l,
        16, 0, 0);
}

// ---------------------------------------------------------------------------
// K0: fused prep.
//   blocks 0..391   : x -> bf16 + per-window mean (2 blocks/window, 128 ch each)
//   blocks 392..439 : Wqkv^T tiles (64x64 LDS transpose); Wk tiles also emit
//                     fp32 WkT[j][c] = Wk[c][j] for the coalesced route path
//   blocks 440..455 : Wo^T tiles
// ---------------------------------------------------------------------------
__global__ __launch_bounds__(256) void k_prep(
    const float* __restrict__ X, unsigned short* __restrict__ Xb,
    float* __restrict__ xmean,
    const float* __restrict__ Wqkv, const float* __restrict__ Wo,
    unsigned short* __restrict__ Wtq, unsigned short* __restrict__ Wto,
    float* __restrict__ WkT)
{
    __shared__ __align__(16) unsigned char sm[64 * 65 * 4];   // 16.6 KB union
    const int t = threadIdx.x;
    const int blk = blockIdx.x;
    if (blk < 392) {
        float* part = (float*)sm;                 // [8 ps][32 cg][4]
        const int w = blk >> 1, hc = blk & 1;
        const int b = w / 49, p = w % 49;
        const int wi = p / 7, wj = p % 7;
        const int ch0 = hc * 128;
        const int ps = t >> 5, cg = t & 31;
        float4 s = {0.f, 0.f, 0.f, 0.f};
        #pragma unroll
        for (int i = 0; i < 8; i++) {
            int pp = ps * 8 + i;
            int y = wi * 8 + (pp >> 3), x = wj * 8 + (pp & 7);
            int idx = (((b * 56) + y) * 56 + x) * 256 + ch0 + cg * 4;
            float4 v = *reinterpret_cast<const float4*>(X + idx);
            s.x += v.x; s.y += v.y; s.z += v.z; s.w += v.w;
            ushort4 o = { f2bf(v.x), f2bf(v.y), f2bf(v.z), f2bf(v.w) };
            *reinterpret_cast<ushort4*>(Xb + idx) = o;
        }
        *reinterpret_cast<float4*>(part + t * 4) = *reinterpret_cast<float4*>(&s);
        __syncthreads();
        if (t < 32) {
            float4 m = {0.f, 0.f, 0.f, 0.f};
            #pragma unroll
            for (int ps2 = 0; ps2 < 8; ps2++) {
                float4 v = *reinterpret_cast<float4*>(part + (ps2 * 32 + t) * 4);
                m.x += v.x; m.y += v.y; m.z += v.z; m.w += v.w;
            }
            m.x *= (1.f / 64.f); m.y *= (1.f / 64.f);
            m.z *= (1.f / 64.f); m.w *= (1.f / 64.f);
            *reinterpret_cast<float4*>(xmean + w * 256 + ch0 + t * 4) = m;
        }
    } else {
        float* tile = (float*)sm;                 // [64][65]
        int tb = blk - 392;
        const float* Wsrc; unsigned short* Wdst; int N, kt, nt;
        if (tb < 48) { Wsrc = Wqkv; Wdst = Wtq; N = 768; kt = tb / 12; nt = tb % 12; }
        else { tb -= 48; Wsrc = Wo; Wdst = Wto; N = 256; kt = tb / 4; nt = tb % 4; }
        const int k0 = kt * 64, n0 = nt * 64;
        const int r0 = t >> 6, c = t & 63;
        #pragma unroll
        for (int i = 0; i < 16; i++) {
            int r = i * 4 + r0;
            tile[r * 65 + c] = Wsrc[(size_t)(k0 + r) * N + n0 + c];
        }
        __syncthreads();
        const bool isWk = (N == 768) && (n0 >= 256) && (n0 < 512);
        #pragma unroll
        for (int i = 0; i < 16; i++) {
            int n = i * 4 + r0;
            float v = tile[c * 65 + n];
            Wdst[(size_t)(n0 + n) * 256 + k0 + c] = f2bf(v);
            if (isWk) WkT[(size_t)(n0 + n - 256) * 256 + k0 + c] = v;
        }
    }
}

// ---------------------------------------------------------------------------
// K1: merged launch — qkv GEMM (blocks 0..587) | winproj+route (blocks 588..783)
//   Route math: logit[p][q] ∝ qwin[p]·kwin[q] = xmean[q]·u,
//   u[c] = Wk[c]·qwin[p];  qwin fp32 exact; u read via fp32 WkT (coalesced).
//   Scale and q-independent bias terms dropped (order-invariant for top-k).
// ---------------------------------------------------------------------------
__global__ __launch_bounds__(256) void k_main1(
    const unsigned short* __restrict__ A,   // xb [12544][256]
    const unsigned short* __restrict__ Bt,  // Wtq [768][256]
    const float* __restrict__ bias,         // bqkv [768]
    unsigned short* __restrict__ O,         // qkv bf16
    const float* __restrict__ xmean,        // [196][256]
    const float* __restrict__ Wqkv,         // fp32 [256][768]
    const float* __restrict__ WkT,          // fp32 [256][256], WkT[j][c]=Wk[c][j]
    int* __restrict__ ridx)
{
    __shared__ __align__(16) unsigned char sm1[16384];
    const int t = threadIdx.x;
    const int blk = blockIdx.x;
    if (blk < 588) {
        unsigned short* As = (unsigned short*)sm1;          // [128*32]
        unsigned short* Bs = (unsigned short*)(sm1 + 8192); // [128*32]
        const int m0 = (blk % 98) * 128, n0 = (blk / 98) * 128;
        const int wave = t >> 6, lane = t & 63, quad = lane >> 4, lo = lane & 15;
        const int wm = wave & 1, wn = wave >> 1;
        const int sr = wave * 16 + (lane >> 2);
        const int sc = lane & 3;
        f32x4 acc[4][4];
        #pragma unroll
        for (int i = 0; i < 4; i++)
            #pragma unroll
            for (int j = 0; j < 4; j++) acc[i][j] = (f32x4){0.f, 0.f, 0.f, 0.f};

        for (int kt = 0; kt < 256; kt += 32) {
            __syncthreads();
            #pragma unroll
            for (int j = 0; j < 2; j++) {
                int row = j * 64 + sr;
                int e = sc ^ ((row >> 1) & 3);
                load_lds16(A  + (size_t)(m0 + row) * 256 + kt + e * 8, &As[row * 32 + sc * 8]);
                load_lds16(Bt + (size_t)(n0 + row) * 256 + kt + e * 8, &Bs[row * 32 + sc * 8]);
            }
            __syncthreads();
            bf16x8 af[4], bfr[4];
            #pragma unroll
            for (int mt = 0; mt < 4; mt++) {
                int row = wm * 64 + mt * 16 + lo;
                int c = quad ^ ((row >> 1) & 3);
                af[mt] = *reinterpret_cast<const bf16x8*>(&As[row * 32 + c * 8]);
            }
            #pragma unroll
            for (int nt = 0; nt < 4; nt++) {
                int col = wn * 64 + nt * 16 + lo;
                int c = quad ^ ((col >> 1) & 3);
                bfr[nt] = *reinterpret_cast<const bf16x8*>(&Bs[col * 32 + c * 8]);
            }
            #pragma unroll
            for (int mt = 0; mt < 4; mt++)
                #pragma unroll
                for (int nt = 0; nt < 4; nt++)
                    acc[mt][nt] = __builtin_amdgcn_mfma_f32_16x16x32_bf16(
                        af[mt], bfr[nt], acc[mt][nt], 0, 0, 0);
        }
        float bv[4];
        #pragma unroll
        for (int nt = 0; nt < 4; nt++) bv[nt] = bias[n0 + wn * 64 + nt * 16 + lo];
        #pragma unroll
        for (int mt = 0; mt < 4; mt++)
            #pragma unroll
            for (int nt = 0; nt < 4; nt++) {
                int n = n0 + wn * 64 + nt * 16 + lo;
                #pragma unroll
                for (int r = 0; r < 4; r++) {
                    int m = m0 + wm * 64 + mt * 16 + quad * 4 + r;
                    O[m * 768 + n] = f2bf(acc[mt][nt][r] + bv[nt]);
                }
            }
    } else {
        float* xq   = (float*)sm1;                 // [256]
        float* qs   = (float*)(sm1 + 1024);        // [256]
        float* us   = (float*)(sm1 + 2048);        // [256]
        float* part = (float*)(sm1 + 3072);        // [49][4]
        float* lg   = (float*)(sm1 + 3072 + 784);  // [49]
        const int u = blk - 588;                   // 0..195 = b*49 + p
        const int b = u / 49;
        xq[t] = xmean[(size_t)u * 256 + t];
        __syncthreads();
        {   // qwin[p][t] (fp32 exact, includes q-bias); coalesced
            float a = 0.f;
            for (int k = 0; k < 256; k++) a += xq[k] * Wqkv[k * 768 + t];
            qs[t] = a + bias[t];
        }
        __syncthreads();
        {   // u[t] = sum_j Wk[t][j]*qs[j] = sum_j WkT[j][t]*qs[j]; coalesced
            float a = 0.f;
            for (int j = 0; j < 256; j++) a += qs[j] * WkT[j * 256 + t];
            us[t] = a;
        }
        __syncthreads();
        if (t < 196) {   // lg[d] = xmean[b,d] · u  (4 partial lanes per d)
            int d = t >> 2, pr = t & 3;
            const float* xm = xmean + (size_t)(b * 49 + d) * 256 + pr * 64;
            float a = 0.f;
            for (int k = 0; k < 64; k++) a += xm[k] * us[pr * 64 + k];
            part[d * 4 + pr] = a;
        }
        __syncthreads();
        if (t < 49) lg[t] = part[t * 4] + part[t * 4 + 1] + part[t * 4 + 2] + part[t * 4 + 3];
        __syncthreads();
        if (t == 0) {
            unsigned long long used = 0ull;
            for (int sel = 0; sel < 4; sel++) {
                float best = -1e30f; int bi = 0;
                for (int qq = 0; qq < 49; qq++)
                    if (!((used >> qq) & 1ull) && lg[qq] > best) { best = lg[qq]; bi = qq; }
                used |= (1ull << bi);
                ridx[u * 4 + sel] = bi;
            }
        }
    }
}

// ---------------------------------------------------------------------------
// K6: MFMA gathered window attention + fused depthwise-5x5 LEPE -> Osum
// ---------------------------------------------------------------------------
__global__ __launch_bounds__(256) void k_attn(
    const unsigned short* __restrict__ QKV,
    const int* __restrict__ ridx,
    const float* __restrict__ lw, const float* __restrict__ lb,
    unsigned short* __restrict__ Osum)
{
    __shared__ __align__(16) unsigned char smem[50688];
    unsigned short* Vt = (unsigned short*)smem;                  // [32][264]
    unsigned short* Qs = (unsigned short*)(smem + 16896);        // [64][40]
    unsigned short* Ks = (unsigned short*)(smem + 22016);        // [256][40]
    unsigned short* Ps = (unsigned short*)(smem + 16896);        // 4 x [16][264]

    const int p = blockIdx.x, head = blockIdx.y, b = blockIdx.z;
    const int t = threadIdx.x;
    const int wi = p / 7, wj = p % 7;
    const int wave = t >> 6, lane = t & 63, quad = lane >> 4, lo = lane & 15;
    const int pix4 = t >> 2, c4 = t & 3;

    {
        int y = wi * 8 + (pix4 >> 3), x = wj * 8 + (pix4 & 7);
        const unsigned short* qp = QKV + (((b * 56) + y) * 56 + x) * 768 + head * 32 + c4 * 8;
        bf16x8 v = *reinterpret_cast<const bf16x8*>(qp);
        int sw = c4 ^ ((pix4 >> 3) & 3);
        *reinterpret_cast<bf16x8*>(&Qs[pix4 * 40 + sw * 8]) = v;
    }
    #pragma unroll
    for (int pass = 0; pass < 4; pass++) {
        int sel = ridx[(b * 49 + p) * 4 + pass];
        int si = sel / 7, sj = sel % 7;
        int y = si * 8 + (pix4 >> 3), x = sj * 8 + (pix4 & 7);
        const unsigned short* base = QKV + (((b * 56) + y) * 56 + x) * 768 + 256 + head * 32;
        bf16x8 kv = *reinterpret_cast<const bf16x8*>(base + c4 * 8);
        bf16x8 vv = *reinterpret_cast<const bf16x8*>(base + 256 + c4 * 8);
        int krow = pass * 64 + pix4;
        int sw = c4 ^ ((krow >> 3) & 3);
        *reinterpret_cast<bf16x8*>(&Ks[krow * 40 + sw * 8]) = kv;
        #pragma unroll
        for (int j = 0; j < 8; j++)
            Vt[(c4 * 8 + j) * 264 + krow] = (unsigned short)vv[j];
    }
    __syncthreads();

    f32x4 sc[16];
    {
        int row = wave * 16 + lo;
        bf16x8 af = *reinterpret_cast<const bf16x8*>(
            &Qs[row * 40 + ((quad ^ ((row >> 3) & 3)) * 8)]);
        f32x4 z = (f32x4){0.f, 0.f, 0.f, 0.f};
        #pragma unroll
        for (int nt = 0; nt < 16; nt++) {
            int key = nt * 16 + lo;
            bf16x8 bfr = *reinterpret_cast<const bf16x8*>(
                &Ks[key * 40 + ((quad ^ ((key >> 3) & 3)) * 8)]);
            sc[nt] = __builtin_amdgcn_mfma_f32_16x16x32_bf16(af, bfr, z, 0, 0, 0);
        }
    }
    float M[4] = {-1e30f, -1e30f, -1e30f, -1e30f};
    #pragma unroll
    for (int nt = 0; nt < 16; nt++)
        #pragma unroll
        for (int r = 0; r < 4; r++) M[r] = fmaxf(M[r], sc[nt][r] * 0.0625f);
    #pragma unroll
    for (int d = 1; d < 16; d <<= 1)
        #pragma unroll
        for (int r = 0; r < 4; r++) M[r] = fmaxf(M[r], __shfl_xor(M[r], d));
    float l[4] = {0.f, 0.f, 0.f, 0.f};
    #pragma unroll
    for (int nt = 0; nt < 16; nt++)
        #pragma unroll
        for (int r = 0; r < 4; r++) {
            float e = __expf(sc[nt][r] * 0.0625f - M[r]);
            sc[nt][r] = e;
            l[r] += e;
        }
    #pragma unroll
    for (int d = 1; d < 16; d <<= 1)
        #pragma unroll
        for (int r = 0; r < 4; r++) l[r] += __shfl_xor(l[r], d);

    __syncthreads();   // all waves done reading Qs/Ks -> Ps may overwrite

    unsigned short* myPs = Ps + wave * 16 * 264;
    #pragma unroll
    for (int nt = 0; nt < 16; nt++)
        #pragma unroll
        for (int r = 0; r < 4; r++)
            myPs[(quad * 4 + r) * 264 + nt * 16 + lo] = f2bf(sc[nt][r]);
    // (no barrier: PV reads only this wave's own Ps tile)

    f32x4 o0 = (f32x4){0.f, 0.f, 0.f, 0.f}, o1 = o0;
    #pragma unroll
    for (int kt = 0; kt < 8; kt++) {
        bf16x8 pa = *reinterpret_cast<const bf16x8*>(
            &myPs[lo * 264 + kt * 32 + quad * 8]);
        bf16x8 vb0 = *reinterpret_cast<const bf16x8*>(
            &Vt[lo * 264 + kt * 32 + quad * 8]);
        bf16x8 vb1 = *reinterpret_cast<const bf16x8*>(
            &Vt[(16 + lo) * 264 + kt * 32 + quad * 8]);
        o0 = __builtin_amdgcn_mfma_f32_16x16x32_bf16(pa, vb0, o0, 0, 0, 0);
        o1 = __builtin_amdgcn_mfma_f32_16x16x32_bf16(pa, vb1, o1, 0, 0, 0);
    }

    // ---- fused LEPE: 12x12 V-halo + bf16 weights into dead LDS regions ----
    __syncthreads();   // everyone done reading Vt / Ps
    unsigned short* Vimg = (unsigned short*)smem;            // [144][40]
    unsigned short* lwsb = (unsigned short*)(smem + 16896);  // [25][32]
    unsigned short* lepb = (unsigned short*)(smem + 18496);  // [64][40]
    if (t < 200) {
        int tap = t >> 3, c = (t & 7) * 4;
        float4 w = *reinterpret_cast<const float4*>(lw + tap * 256 + head * 32 + c);
        unsigned short* dst = &lwsb[tap * 32 + c];
        dst[0] = f2bf(w.x); dst[1] = f2bf(w.y); dst[2] = f2bf(w.z); dst[3] = f2bf(w.w);
    }
    {
        const int y0 = wi * 8 - 2, x0 = wj * 8 - 2;
        #pragma unroll
        for (int i = 0; i < 3; i++) {
            int idx = i * 256 + t;
            if (idx < 576) {
                int pp = idx >> 2, cc = idx & 3;
                int py = y0 + pp / 12, px = x0 + pp % 12;
                bf16x8 v = (bf16x8){0, 0, 0, 0, 0, 0, 0, 0};
                if (py >= 0 && py < 56 && px >= 0 && px < 56)
                    v = *reinterpret_cast<const bf16x8*>(
                        QKV + (((b * 56) + py) * 56 + px) * 768 + 512 + head * 32 + cc * 8);
                *reinterpret_cast<bf16x8*>(&Vimg[pp * 40 + cc * 8]) = v;
            }
        }
    }
    __syncthreads();
    {   // depthwise 5x5 for own 64 pixels, 8 ch per thread
        const int qpix = t >> 2, cc = t & 3;
        const int qy = qpix >> 3, qx = qpix & 7;
        float accl[8];
        float4 b0 = *reinterpret_cast<const float4*>(lb + head * 32 + cc * 8);
        float4 b1 = *reinterpret_cast<const float4*>(lb + head * 32 + cc * 8 + 4);
        accl[0] = b0.x; accl[1] = b0.y; accl[2] = b0.z; accl[3] = b0.w;
        accl[4] = b1.x; accl[5] = b1.y; accl[6] = b1.z; accl[7] = b1.w;
        #pragma unroll
        for (int ky = 0; ky < 5; ky++)
            #pragma unroll
            for (int kx = 0; kx < 5; kx++) {
                int pp = (qy + ky) * 12 + (qx + kx);
                bf16x8 v = *reinterpret_cast<const bf16x8*>(&Vimg[pp * 40 + cc * 8]);
                bf16x8 w = *reinterpret_cast<const bf16x8*>(&lwsb[(ky * 5 + kx) * 32 + cc * 8]);
                #pragma unroll
                for (int j = 0; j < 8; j++)
                    accl[j] += bf2f((unsigned short)v[j]) * bf2f((unsigned short)w[j]);
            }
        bf16x8 o;
        #pragma unroll
        for (int j = 0; j < 8; j++) o[j] = (short)f2bf(accl[j]);
        *reinterpret_cast<bf16x8*>(&lepb[qpix * 40 + cc * 8]) = o;
    }
    __syncthreads();

    #pragma unroll
    for (int r = 0; r < 4; r++) {
        int q = wave * 16 + quad * 4 + r;
        int y = wi * 8 + (q >> 3), x = wj * 8 + (q & 7);
        unsigned short* op = Osum + (size_t)(((b * 56) + y) * 56 + x) * 256 + head * 32;
        float inv = 1.0f / l[r];
        float le0 = bf2f(lepb[q * 40 + lo]);
        float le1 = bf2f(lepb[q * 40 + 16 + lo]);
        op[lo]      = f2bf(o0[r] * inv + le0);
        op[16 + lo] = f2bf(o1[r] * inv + le1);
    }
}

// ---------------------------------------------------------------------------
// K7: out proj (MFMA): Osum[12544,256] @ Wo[256,256] + bo -> fp32 out
// ---------------------------------------------------------------------------
__global__ __launch_bounds__(256) void k_proj(
    const unsigned short* __restrict__ A,
    const unsigned short* __restrict__ Bt,   // Wto [256][256]
    const float* __restrict__ bias,
    float* __restrict__ O)
{
    __shared__ unsigned short As[128 * 32];
    __shared__ unsigned short Bs[64 * 32];
    const int t = threadIdx.x;
    const int m0 = blockIdx.x * 128, n0 = blockIdx.y * 64;
    const int wave = t >> 6, lane = t & 63, quad = lane >> 4, lo = lane & 15;
    const int sr = wave * 16 + (lane >> 2);
    const int sc = lane & 3;
    f32x4 acc[2][4];
    #pragma unroll
    for (int i = 0; i < 2; i++)
        #pragma unroll
        for (int j = 0; j < 4; j++) acc[i][j] = (f32x4){0.f, 0.f, 0.f, 0.f};

    for (int kt = 0; kt < 256; kt += 32) {
        __syncthreads();
        #pragma unroll
        for (int j = 0; j < 2; j++) {
            int row = j * 64 + sr;
            int e = sc ^ ((row >> 1) & 3);
            load_lds16(A + (size_t)(m0 + row) * 256 + kt + e * 8, &As[row * 32 + sc * 8]);
        }
        {
            int e = sc ^ ((sr >> 1) & 3);
            load_lds16(Bt + (size_t)(n0 + sr) * 256 + kt + e * 8, &Bs[sr * 32 + sc * 8]);
        }
        __syncthreads();
        bf16x8 af[2], bfr[4];
        #pragma unroll
        for (int mt = 0; mt < 2; mt++) {
            int row = wave * 32 + mt * 16 + lo;
            int c = quad ^ ((row >> 1) & 3);
            af[mt] = *reinterpret_cast<const bf16x8*>(&As[row * 32 + c * 8]);
        }
        #pragma unroll
        for (int nt = 0; nt < 4; nt++) {
            int col = nt * 16 + lo;
            int c = quad ^ ((col >> 1) & 3);
            bfr[nt] = *reinterpret_cast<const bf16x8*>(&Bs[col * 32 + c * 8]);
        }
        #pragma unroll
        for (int mt = 0; mt < 2; mt++)
            #pragma unroll
            for (int nt = 0; nt < 4; nt++)
                acc[mt][nt] = __builtin_amdgcn_mfma_f32_16x16x32_bf16(
                    af[mt], bfr[nt], acc[mt][nt], 0, 0, 0);
    }
    float bv[4];
    #pragma unroll
    for (int nt = 0; nt < 4; nt++) bv[nt] = bias[n0 + nt * 16 + lo];
    #pragma unroll
    for (int mt = 0; mt < 2; mt++)
        #pragma unroll
        for (int nt = 0; nt < 4; nt++) {
            int n = n0 + nt * 16 + lo;
            #pragma unroll
            for (int r = 0; r < 4; r++) {
                int m = m0 + wave * 32 + mt * 16 + quad * 4 + r;
                O[m * 256 + n] = acc[mt][nt][r] + bv[nt];
            }
        }
}

// ---------------------------------------------------------------------------
extern "C" void kernel_launch(void* const* d_in, const int* in_sizes, int n_in,
                              void* d_out, int out_size, void* d_ws, size_t ws_size,
                              hipStream_t stream)
{
    const float* x    = (const float*)d_in[0];
    const float* Wqkv = (const float*)d_in[1];
    const float* bqkv = (const float*)d_in[2];
    const float* Wo   = (const float*)d_in[3];
    const float* bo   = (const float*)d_in[4];
    const float* lw   = (const float*)d_in[5];
    const float* lb   = (const float*)d_in[6];
    float* out = (float*)d_out;

    char* ws = (char*)d_ws;
    size_t off = 0;
    unsigned short* qkv   = (unsigned short*)(ws + off); off += (size_t)NPIX * 768 * 2;
    unsigned short* xb    = (unsigned short*)(ws + off); off += (size_t)NPIX * 256 * 2;
    unsigned short* Wtq   = (unsigned short*)(ws + off); off += 768 * 256 * 2;
    unsigned short* Wto   = (unsigned short*)(ws + off); off += 256 * 256 * 2;
    unsigned short* Osum  = (unsigned short*)(ws + off); off += (size_t)NPIX * 256 * 2;
    float* WkT   = (float*)(ws + off); off += 256 * 256 * 4;
    float* xmean = (float*)(ws + off); off += 196 * 256 * 4;
    int*   ridx  = (int*)(ws + off);   off += 196 * 4 * 4;

    k_prep <<<dim3(456),      256, 0, stream>>>(x, xb, xmean, Wqkv, Wo, Wtq, Wto, WkT);
    k_main1<<<dim3(784),      256, 0, stream>>>(xb, Wtq, bqkv, qkv, xmean, Wqkv, WkT, ridx);
    k_attn <<<dim3(49, 8, 4), 256, 0, stream>>>(qkv, ridx, lw, lb, Osum);
    k_proj <<<dim3(98, 4),    256, 0, stream>>>(Osum, Wto, bo, out);
}